// Round 1
// 257.062 us; speedup vs baseline: 1.3907x; 1.3907x over previous
//
#include <hip/hip_runtime.h>

#define N_NODES 50000
#define N_EDGES 800000
#define D 64

// ---------------------------------------------------------------------------
// Workspace layout (bytes) — total ~4.4 MB (prev version used 13.2 MB):
//   [0,       200000)   out_deg : int[N_NODES]
//   [200000,  400000)   in_deg  : int[N_NODES]
//   [400000,  400064)   ctr     : int (global scan counter) + pad
//   [400064,  600064)   base    : int[N_NODES]   CSR row start
//   [600064,  800064)   cursor  : int[N_NODES]   fill cursor (== row end after fill)
//   [800064, 1000064)   snorm   : float[N_NODES] rsqrt(max(out_deg,1))
//   [1000064,1200064)   dnorm   : float[N_NODES] rsqrt(max(in_deg,1))
//   [1200064,4400064)   ssrc    : int[N_EDGES]   src ids grouped by dst
// Only [0, 400064) needs zeroing.
// ---------------------------------------------------------------------------
#define OUTDEG_OFF 0
#define INDEG_OFF  200000
#define CTR_OFF    400000
#define BASE_OFF   400064
#define CUR_OFF    600064
#define SNORM_OFF  800064
#define DNORM_OFF  1000064
#define SSRC_OFF   1200064
#define ZERO_BYTES 400064

// Pass 1: degrees. int4-vectorized edge reads, 8 int atomics / thread.
__global__ __launch_bounds__(256) void degree_kernel(const int4* __restrict__ src4,
                                                     const int4* __restrict__ dst4,
                                                     int* __restrict__ outdeg,
                                                     int* __restrict__ indeg) {
    int i = blockIdx.x * blockDim.x + threadIdx.x;
    if (i < N_EDGES / 4) {
        int4 s = src4[i], t = dst4[i];
        atomicAdd(&outdeg[s.x], 1); atomicAdd(&outdeg[s.y], 1);
        atomicAdd(&outdeg[s.z], 1); atomicAdd(&outdeg[s.w], 1);
        atomicAdd(&indeg[t.x], 1);  atomicAdd(&indeg[t.y], 1);
        atomicAdd(&indeg[t.z], 1);  atomicAdd(&indeg[t.w], 1);
    }
}

// Pass 2: per-wave exclusive scan of in_deg → CSR bases (order across waves is
// arbitrary via the global counter — a valid, just unordered, CSR). Also emits
// both normalization vectors.
__global__ __launch_bounds__(256) void scan_kernel(const int* __restrict__ outdeg,
                                                   const int* __restrict__ indeg,
                                                   int* __restrict__ base,
                                                   int* __restrict__ cursor,
                                                   float* __restrict__ snorm,
                                                   float* __restrict__ dnorm,
                                                   int* __restrict__ ctr) {
    int n = blockIdx.x * blockDim.x + threadIdx.x;
    int lane = threadIdx.x & 63;
    int d = (n < N_NODES) ? indeg[n] : 0;
    int sum = d;  // inclusive wave scan
#pragma unroll
    for (int off = 1; off < 64; off <<= 1) {
        int v = __shfl_up(sum, off);
        if (lane >= off) sum += v;
    }
    int wtot = __shfl(sum, 63);
    int wbase = 0;
    if (lane == 63) wbase = atomicAdd(ctr, wtot);
    wbase = __shfl(wbase, 63);
    if (n < N_NODES) {
        int myb = wbase + (sum - d);  // exclusive
        base[n] = myb;
        cursor[n] = myb;
        dnorm[n] = rsqrtf(fmaxf((float)d, 1.0f));
        snorm[n] = rsqrtf(fmaxf((float)outdeg[n], 1.0f));
    }
}

// Pass 3: bucket src ids by dst. 800K int atomics (16x less atomic traffic than
// the old 51.2M float-lane scatter), scattered 4B writes into L2-resident 3.2MB.
__global__ __launch_bounds__(256) void fill_kernel(const int4* __restrict__ src4,
                                                   const int4* __restrict__ dst4,
                                                   int* __restrict__ cursor,
                                                   int* __restrict__ ssrc) {
    int i = blockIdx.x * blockDim.x + threadIdx.x;
    if (i < N_EDGES / 4) {
        int4 s = src4[i], t = dst4[i];
        int p0 = atomicAdd(&cursor[t.x], 1);
        int p1 = atomicAdd(&cursor[t.y], 1);
        int p2 = atomicAdd(&cursor[t.z], 1);
        int p3 = atomicAdd(&cursor[t.w], 1);
        ssrc[p0] = s.x; ssrc[p1] = s.y; ssrc[p2] = s.z; ssrc[p3] = s.w;
    }
}

// Pass 4 (fused aggregate + matmul + bias): one wave per dst node, lane = feature.
// Gather x rows (coalesced 256B per edge, L2/L3-resident) into registers — zero
// atomics. Then out_row = dnorm * (acc @ W) + b with W held as one column per
// lane in 64 VGPRs; acc broadcast across lanes via v_readlane. No LDS at all.
#define GBLK 1024
__global__ __launch_bounds__(256, 4) void gather_mm_kernel(const float* __restrict__ x,
                                                           const int* __restrict__ ssrc,
                                                           const int* __restrict__ base,
                                                           const int* __restrict__ cursor,
                                                           const float* __restrict__ snorm,
                                                           const float* __restrict__ dnorm,
                                                           const float* __restrict__ W,
                                                           const float* __restrict__ b,
                                                           float* __restrict__ out) {
    int lane = threadIdx.x & 63;
    int wave = (blockIdx.x << 2) | (threadIdx.x >> 6);

    // Lane j holds W[:, j] — loaded coalesced (256B per k), once per wave.
    float Wreg[D];
#pragma unroll
    for (int k = 0; k < D; k++) Wreg[k] = W[k * D + lane];
    float breg = b[lane];
    const float* xl = x + lane;

    for (int n = wave; n < N_NODES; n += GBLK * 4) {
        int beg = base[n];
        int end = cursor[n];  // after fill, cursor == row end
        float a0 = 0.f, a1 = 0.f, a2 = 0.f, a3 = 0.f;
        int i = beg;
        for (; i + 4 <= end; i += 4) {  // 4 independent gathers in flight
            int s0 = ssrc[i], s1 = ssrc[i + 1], s2 = ssrc[i + 2], s3 = ssrc[i + 3];
            a0 = fmaf(xl[s0 * D], snorm[s0], a0);
            a1 = fmaf(xl[s1 * D], snorm[s1], a1);
            a2 = fmaf(xl[s2 * D], snorm[s2], a2);
            a3 = fmaf(xl[s3 * D], snorm[s3], a3);
        }
        for (; i < end; ++i) {
            int s = ssrc[i];
            a0 = fmaf(xl[s * D], snorm[s], a0);
        }
        float acc = (a0 + a1) + (a2 + a3);

        int accb = __float_as_int(acc);
        float p0 = 0.f, p1 = 0.f, p2 = 0.f, p3 = 0.f;
#pragma unroll
        for (int k = 0; k < D; k += 4) {  // 4 partial sums break the FMA dep chain
            p0 = fmaf(__int_as_float(__builtin_amdgcn_readlane(accb, k + 0)), Wreg[k + 0], p0);
            p1 = fmaf(__int_as_float(__builtin_amdgcn_readlane(accb, k + 1)), Wreg[k + 1], p1);
            p2 = fmaf(__int_as_float(__builtin_amdgcn_readlane(accb, k + 2)), Wreg[k + 2], p2);
            p3 = fmaf(__int_as_float(__builtin_amdgcn_readlane(accb, k + 3)), Wreg[k + 3], p3);
        }
        float sum = (p0 + p1) + (p2 + p3);
        out[(size_t)n * D + lane] = fmaf(sum, dnorm[n], breg);
    }
}

extern "C" void kernel_launch(void* const* d_in, const int* in_sizes, int n_in,
                              void* d_out, int out_size, void* d_ws, size_t ws_size,
                              hipStream_t stream) {
    const float* x   = (const float*)d_in[0];
    const int*   src = (const int*)d_in[1];
    const int*   dst = (const int*)d_in[2];
    const float* W   = (const float*)d_in[3];
    const float* b   = (const float*)d_in[4];
    float* out = (float*)d_out;

    char* ws = (char*)d_ws;
    int*   outdeg = (int*)(ws + OUTDEG_OFF);
    int*   indeg  = (int*)(ws + INDEG_OFF);
    int*   ctr    = (int*)(ws + CTR_OFF);
    int*   base   = (int*)(ws + BASE_OFF);
    int*   cur    = (int*)(ws + CUR_OFF);
    float* snorm  = (float*)(ws + SNORM_OFF);
    float* dnorm  = (float*)(ws + DNORM_OFF);
    int*   ssrc   = (int*)(ws + SSRC_OFF);

    // Only degrees + counter need zeroing (ws is poisoned before every call).
    hipMemsetAsync(d_ws, 0, ZERO_BYTES, stream);

    {
        int threads = 256;
        int blocks = (N_EDGES / 4 + threads - 1) / threads;  // 782
        degree_kernel<<<blocks, threads, 0, stream>>>((const int4*)src, (const int4*)dst,
                                                      outdeg, indeg);
    }
    {
        int threads = 256;
        int blocks = (N_NODES + threads - 1) / threads;  // 196
        scan_kernel<<<blocks, threads, 0, stream>>>(outdeg, indeg, base, cur,
                                                    snorm, dnorm, ctr);
    }
    {
        int threads = 256;
        int blocks = (N_EDGES / 4 + threads - 1) / threads;  // 782
        fill_kernel<<<blocks, threads, 0, stream>>>((const int4*)src, (const int4*)dst,
                                                    cur, ssrc);
    }
    {
        gather_mm_kernel<<<GBLK, 256, 0, stream>>>(x, ssrc, base, cur,
                                                   snorm, dnorm, W, b, out);
    }
}

// Round 2
// 186.405 us; speedup vs baseline: 1.9179x; 1.3790x over previous
//
#include <hip/hip_runtime.h>

#define N_NODES 50000
#define N_EDGES 800000
#define D 64

#define SLICES 64            // edge slices per role (src/dst)
#define I4_PER_SLICE (N_EDGES / 4 / SLICES)   // 3125 int4 per slice
#define NWORDS 12512         // ceil(50000/4)=12500 words, padded to 12512

// ---------------------------------------------------------------------------
// Workspace layout (bytes), total ~10.4 MB:
//   [0,        64)        ctr     : int (scan counter)            [zeroed]
//   [64,       200064)    base    : int[N_NODES]
//   [200064,   400064)    cursor  : int[N_NODES]
//   [400064,   600064)    snorm   : float[N_NODES]
//   [600064,   800064)    dnorm   : float[N_NODES]
//   [800064,   4000064)   ssrc    : int[N_EDGES]
//   [4000064,  10406208)  partial : uint[128][NWORDS] byte-packed histograms
// Only ctr needs zeroing.
// ---------------------------------------------------------------------------
#define CTR_OFF    0
#define BASE_OFF   64
#define CUR_OFF    200064
#define SNORM_OFF  400064
#define DNORM_OFF  600064
#define SSRC_OFF   800064
#define PART_OFF   4000064
#define ZERO_BYTES 64

// Pass 1: per-slice byte-packed degree histograms in LDS (no fabric atomics).
// Block b: role = b&1 (0=outdeg from src, 1=indeg from dst), slice = b>>1.
__global__ __launch_bounds__(256) void degree_lds_kernel(const int4* __restrict__ src4,
                                                         const int4* __restrict__ dst4,
                                                         unsigned int* __restrict__ partial) {
    __shared__ unsigned int hist[NWORDS];   // 50 KB: byte counts for all 50K nodes
    int tid = threadIdx.x;
    for (int i = tid; i < NWORDS; i += 256) hist[i] = 0;
    __syncthreads();

    int role  = blockIdx.x & 1;
    int slice = blockIdx.x >> 1;
    const int4* e = role ? dst4 : src4;
    int beg = slice * I4_PER_SLICE, end = beg + I4_PER_SLICE;
    for (int i = beg + tid; i < end; i += 256) {
        int4 v = e[i];
        atomicAdd(&hist[v.x >> 2], 1u << ((v.x & 3) * 8));
        atomicAdd(&hist[v.y >> 2], 1u << ((v.y & 3) * 8));
        atomicAdd(&hist[v.z >> 2], 1u << ((v.z & 3) * 8));
        atomicAdd(&hist[v.w >> 2], 1u << ((v.w & 3) * 8));
    }
    __syncthreads();

    unsigned int* p = partial + (size_t)blockIdx.x * NWORDS;
    for (int i = tid; i < NWORDS; i += 256) p[i] = hist[i];   // coalesced
}

// Pass 2 (fused merge + scan): sum the 64 byte-packed partials per role,
// emit norms, wave-scan in_deg -> CSR bases (unordered-but-valid CSR).
__global__ __launch_bounds__(256) void merge_scan_kernel(const unsigned int* __restrict__ partial,
                                                         int* __restrict__ base,
                                                         int* __restrict__ cursor,
                                                         float* __restrict__ snorm,
                                                         float* __restrict__ dnorm,
                                                         int* __restrict__ ctr) {
    int n = blockIdx.x * blockDim.x + threadIdx.x;
    int lane = threadIdx.x & 63;
    int din = 0, dout = 0;
    if (n < N_NODES) {
        int w = n >> 2, sh = (n & 3) * 8;
        const unsigned int* po = partial + w;
#pragma unroll 8
        for (int s = 0; s < SLICES; s++) {
            dout += (po[(size_t)(2 * s) * NWORDS] >> sh) & 0xFFu;
            din  += (po[(size_t)(2 * s + 1) * NWORDS] >> sh) & 0xFFu;
        }
    }
    int sum = din;  // inclusive wave scan
#pragma unroll
    for (int off = 1; off < 64; off <<= 1) {
        int v = __shfl_up(sum, off);
        if (lane >= off) sum += v;
    }
    int wtot = __shfl(sum, 63);
    int wbase = 0;
    if (lane == 63) wbase = atomicAdd(ctr, wtot);
    wbase = __shfl(wbase, 63);
    if (n < N_NODES) {
        int myb = wbase + (sum - din);  // exclusive
        base[n] = myb;
        cursor[n] = myb;
        dnorm[n] = rsqrtf(fmaxf((float)din, 1.0f));
        snorm[n] = rsqrtf(fmaxf((float)dout, 1.0f));
    }
}

// Pass 3: bucket src ids by dst (800K returning atomics, L2-resident cursors).
__global__ __launch_bounds__(256) void fill_kernel(const int4* __restrict__ src4,
                                                   const int4* __restrict__ dst4,
                                                   int* __restrict__ cursor,
                                                   int* __restrict__ ssrc) {
    int i = blockIdx.x * blockDim.x + threadIdx.x;
    if (i < N_EDGES / 4) {
        int4 s = src4[i], t = dst4[i];
        int p0 = atomicAdd(&cursor[t.x], 1);
        int p1 = atomicAdd(&cursor[t.y], 1);
        int p2 = atomicAdd(&cursor[t.z], 1);
        int p3 = atomicAdd(&cursor[t.w], 1);
        ssrc[p0] = s.x; ssrc[p1] = s.y; ssrc[p2] = s.z; ssrc[p3] = s.w;
    }
}

// Pass 4 (fused gather + matmul + bias): one wave per dst node, lane = feature.
// 8 independent row-gathers in flight; W held one column per lane in VGPRs;
// acc broadcast via v_readlane. No LDS, zero atomics.
#define GBLK 1024
__global__ __launch_bounds__(256, 4) void gather_mm_kernel(const float* __restrict__ x,
                                                           const int* __restrict__ ssrc,
                                                           const int* __restrict__ base,
                                                           const int* __restrict__ cursor,
                                                           const float* __restrict__ snorm,
                                                           const float* __restrict__ dnorm,
                                                           const float* __restrict__ W,
                                                           const float* __restrict__ b,
                                                           float* __restrict__ out) {
    int lane = threadIdx.x & 63;
    int wave = (blockIdx.x << 2) | (threadIdx.x >> 6);

    float Wreg[D];
#pragma unroll
    for (int k = 0; k < D; k++) Wreg[k] = W[k * D + lane];
    float breg = b[lane];
    const float* xl = x + lane;

    for (int n = wave; n < N_NODES; n += GBLK * 4) {
        int beg = base[n];
        int end = cursor[n];
        float a0 = 0.f, a1 = 0.f, a2 = 0.f, a3 = 0.f;
        float a4 = 0.f, a5 = 0.f, a6 = 0.f, a7 = 0.f;
        int i = beg;
        for (; i + 8 <= end; i += 8) {   // 8 gathers in flight
            int s0 = ssrc[i],     s1 = ssrc[i + 1], s2 = ssrc[i + 2], s3 = ssrc[i + 3];
            int s4 = ssrc[i + 4], s5 = ssrc[i + 5], s6 = ssrc[i + 6], s7 = ssrc[i + 7];
            a0 = fmaf(xl[s0 * D], snorm[s0], a0);
            a1 = fmaf(xl[s1 * D], snorm[s1], a1);
            a2 = fmaf(xl[s2 * D], snorm[s2], a2);
            a3 = fmaf(xl[s3 * D], snorm[s3], a3);
            a4 = fmaf(xl[s4 * D], snorm[s4], a4);
            a5 = fmaf(xl[s5 * D], snorm[s5], a5);
            a6 = fmaf(xl[s6 * D], snorm[s6], a6);
            a7 = fmaf(xl[s7 * D], snorm[s7], a7);
        }
        for (; i + 4 <= end; i += 4) {
            int s0 = ssrc[i], s1 = ssrc[i + 1], s2 = ssrc[i + 2], s3 = ssrc[i + 3];
            a0 = fmaf(xl[s0 * D], snorm[s0], a0);
            a1 = fmaf(xl[s1 * D], snorm[s1], a1);
            a2 = fmaf(xl[s2 * D], snorm[s2], a2);
            a3 = fmaf(xl[s3 * D], snorm[s3], a3);
        }
        for (; i < end; ++i) {
            int s = ssrc[i];
            a0 = fmaf(xl[s * D], snorm[s], a0);
        }
        float acc = ((a0 + a4) + (a1 + a5)) + ((a2 + a6) + (a3 + a7));

        int accb = __float_as_int(acc);
        float p0 = 0.f, p1 = 0.f, p2 = 0.f, p3 = 0.f;
#pragma unroll
        for (int k = 0; k < D; k += 4) {
            p0 = fmaf(__int_as_float(__builtin_amdgcn_readlane(accb, k + 0)), Wreg[k + 0], p0);
            p1 = fmaf(__int_as_float(__builtin_amdgcn_readlane(accb, k + 1)), Wreg[k + 1], p1);
            p2 = fmaf(__int_as_float(__builtin_amdgcn_readlane(accb, k + 2)), Wreg[k + 2], p2);
            p3 = fmaf(__int_as_float(__builtin_amdgcn_readlane(accb, k + 3)), Wreg[k + 3], p3);
        }
        float sum = (p0 + p1) + (p2 + p3);
        out[(size_t)n * D + lane] = fmaf(sum, dnorm[n], breg);
    }
}

extern "C" void kernel_launch(void* const* d_in, const int* in_sizes, int n_in,
                              void* d_out, int out_size, void* d_ws, size_t ws_size,
                              hipStream_t stream) {
    const float* x   = (const float*)d_in[0];
    const int*   src = (const int*)d_in[1];
    const int*   dst = (const int*)d_in[2];
    const float* W   = (const float*)d_in[3];
    const float* b   = (const float*)d_in[4];
    float* out = (float*)d_out;

    char* ws = (char*)d_ws;
    int*          ctr    = (int*)(ws + CTR_OFF);
    int*          base   = (int*)(ws + BASE_OFF);
    int*          cur    = (int*)(ws + CUR_OFF);
    float*        snorm  = (float*)(ws + SNORM_OFF);
    float*        dnorm  = (float*)(ws + DNORM_OFF);
    int*          ssrc   = (int*)(ws + SSRC_OFF);
    unsigned int* part   = (unsigned int*)(ws + PART_OFF);

    // Only the scan counter needs zeroing.
    hipMemsetAsync(d_ws, 0, ZERO_BYTES, stream);

    {
        // 64 slices x 2 roles = 128 blocks, full 50K-node byte histogram each.
        degree_lds_kernel<<<2 * SLICES, 256, 0, stream>>>((const int4*)src,
                                                          (const int4*)dst, part);
    }
    {
        int blocks = (N_NODES + 255) / 256;  // 196
        merge_scan_kernel<<<blocks, 256, 0, stream>>>(part, base, cur, snorm, dnorm, ctr);
    }
    {
        int blocks = (N_EDGES / 4 + 255) / 256;  // 782
        fill_kernel<<<blocks, 256, 0, stream>>>((const int4*)src, (const int4*)dst,
                                                cur, ssrc);
    }
    {
        gather_mm_kernel<<<GBLK, 256, 0, stream>>>(x, ssrc, base, cur,
                                                   snorm, dnorm, W, b, out);
    }
}

// Round 3
// 171.712 us; speedup vs baseline: 2.0820x; 1.0856x over previous
//
#include <hip/hip_runtime.h>
#include <hip/hip_fp16.h>

#define N_NODES 50000
#define N_EDGES 800000
#define D 64

#define SLICES 80                      // edge slices per role (src/dst)
#define I4S (N_EDGES / 4 / SLICES)     // 2500 int4 per slice (10000 edges)
#define NWORDS 12512                   // ceil(50000/4)=12500 words, padded

// ---------------------------------------------------------------------------
// Workspace layout (bytes), total ~12.1 MB:
//   [0,       64)        ctr    : int (scan counter)                 [zeroed]
//   [64,      200064)    base   : int[N_NODES]   CSR row start
//   [200064,  400064)    rend   : int[N_NODES]   CSR row end
//   [400064,  600064)    snorm  : float[N_NODES]
//   [600064,  800064)    dnorm  : float[N_NODES]
//   [800064,  850112)    INW    : uint[NWORDS]   packed in-degree
//   [850112,  900160)    OUTW   : uint[NWORDS]   packed out-degree
//   [900160,  4100160)   ssrc   : int[N_EDGES]   src ids grouped by dst
//   [4100160, 12107840)  partial: uint[160][NWORDS] byte histograms → prefixes
//   [4100160, 10500160)  y16    : half[N_NODES*D]  (ALIASES partial — partial
//                                 is dead once fill_kernel has run)
// ---------------------------------------------------------------------------
#define CTR_OFF    0
#define BASE_OFF   64
#define END_OFF    200064
#define SNORM_OFF  400064
#define DNORM_OFF  600064
#define INW_OFF    800064
#define OUTW_OFF   850112
#define SSRC_OFF   900160
#define PART_OFF   4100160
#define Y16_OFF    PART_OFF
#define ZERO_BYTES 64

// Pass 1: per-slice byte-packed degree histograms in LDS. No fabric atomics.
// Block b: role = b&1 (0=src/outdeg, 1=dst/indeg), slice = b>>1.
__global__ __launch_bounds__(256) void degree_lds_kernel(const int4* __restrict__ src4,
                                                         const int4* __restrict__ dst4,
                                                         unsigned int* __restrict__ partial) {
    __shared__ unsigned int hist[NWORDS];
    int tid = threadIdx.x;
    for (int i = tid; i < NWORDS; i += 256) hist[i] = 0;
    __syncthreads();

    int role  = blockIdx.x & 1;
    int slice = blockIdx.x >> 1;
    const int4* e = role ? dst4 : src4;
    int beg = slice * I4S, end = beg + I4S;
    for (int i = beg + tid; i < end; i += 256) {
        int4 v = e[i];
        atomicAdd(&hist[v.x >> 2], 1u << ((v.x & 3) * 8));
        atomicAdd(&hist[v.y >> 2], 1u << ((v.y & 3) * 8));
        atomicAdd(&hist[v.z >> 2], 1u << ((v.z & 3) * 8));
        atomicAdd(&hist[v.w >> 2], 1u << ((v.w & 3) * 8));
    }
    __syncthreads();

    unsigned int* p = partial + (size_t)blockIdx.x * NWORDS;
    for (int i = tid; i < NWORDS; i += 256) p[i] = hist[i];
}

// Pass 2: thread-per-word merge. Sums packed degrees for both roles AND
// rewrites the dst-role partials in place to per-slice EXCLUSIVE prefixes
// (packed byte adds — cumulative <= indeg < 255, so no carry between bytes).
__global__ __launch_bounds__(256) void merge_kernel(unsigned int* __restrict__ partial,
                                                    unsigned int* __restrict__ INW,
                                                    unsigned int* __restrict__ OUTW) {
    int w = blockIdx.x * blockDim.x + threadIdx.x;
    if (w >= 12500) return;
    unsigned int accin = 0, accout = 0;
#pragma unroll 4
    for (int s = 0; s < SLICES; s++) {
        size_t od = (size_t)(2 * s) * NWORDS + w;
        size_t dd = (size_t)(2 * s + 1) * NWORDS + w;
        accout += partial[od];
        unsigned int v = partial[dd];
        partial[dd] = accin;        // exclusive prefix before slice s
        accin += v;
    }
    INW[w] = accin;
    OUTW[w] = accout;
}

// Pass 3: thread-per-node wave scan of in-degree -> CSR bases; emit norms.
__global__ __launch_bounds__(256) void scan_kernel(const unsigned int* __restrict__ INW,
                                                   const unsigned int* __restrict__ OUTW,
                                                   int* __restrict__ base,
                                                   int* __restrict__ rend,
                                                   float* __restrict__ snorm,
                                                   float* __restrict__ dnorm,
                                                   int* __restrict__ ctr) {
    int n = blockIdx.x * blockDim.x + threadIdx.x;
    int lane = threadIdx.x & 63;
    int din = 0, dout = 0;
    if (n < N_NODES) {
        int sh = (n & 3) * 8;
        din  = (INW[n >> 2] >> sh) & 0xFF;
        dout = (OUTW[n >> 2] >> sh) & 0xFF;
    }
    int sum = din;  // inclusive wave scan
#pragma unroll
    for (int off = 1; off < 64; off <<= 1) {
        int v = __shfl_up(sum, off);
        if (lane >= off) sum += v;
    }
    int wtot = __shfl(sum, 63);
    int wbase = 0;
    if (lane == 63) wbase = atomicAdd(ctr, wtot);
    wbase = __shfl(wbase, 63);
    if (n < N_NODES) {
        int myb = wbase + (sum - din);  // exclusive
        base[n] = myb;
        rend[n] = myb + din;
        dnorm[n] = rsqrtf(fmaxf((float)din, 1.0f));
        snorm[n] = rsqrtf(fmaxf((float)dout, 1.0f));
    }
}

// Pass 4: CSR fill with ZERO fabric atomics. Block = dst slice; position =
// base[t] + prefix_slice[t] + LDS-local occurrence index (byte-packed).
__global__ __launch_bounds__(256) void fill_kernel(const int4* __restrict__ src4,
                                                   const int4* __restrict__ dst4,
                                                   const unsigned int* __restrict__ partial,
                                                   const int* __restrict__ base,
                                                   int* __restrict__ ssrc) {
    __shared__ unsigned int hist[NWORDS];
    int tid = threadIdx.x;
    for (int i = tid; i < NWORDS; i += 256) hist[i] = 0;
    __syncthreads();

    int s = blockIdx.x;
    const int4* sp = src4 + (size_t)s * I4S;
    const int4* dp = dst4 + (size_t)s * I4S;
    const unsigned int* pref = partial + (size_t)(2 * s + 1) * NWORDS;

    for (int i = tid; i < I4S; i += 256) {
        int4 sv = sp[i], tv = dp[i];
#define FILL_ONE(T, S)                                                        \
        {                                                                     \
            int t = (T); int sh = (t & 3) * 8;                                \
            unsigned int old = atomicAdd(&hist[t >> 2], 1u << sh);            \
            int local = (old >> sh) & 0xFF;                                   \
            int p = base[t] + (int)((pref[t >> 2] >> sh) & 0xFFu) + local;    \
            ssrc[p] = (S);                                                    \
        }
        FILL_ONE(tv.x, sv.x)
        FILL_ONE(tv.y, sv.y)
        FILL_ONE(tv.z, sv.z)
        FILL_ONE(tv.w, sv.w)
#undef FILL_ONE
    }
}

// Pass 5: y = (x * snorm) @ W, stored fp16. Wave per node, lane = out column;
// W one column per lane in VGPRs, x-row broadcast via v_readlane.
#define YBLK 1024
__global__ __launch_bounds__(256, 4) void y_kernel(const float* __restrict__ x,
                                                   const float* __restrict__ snorm,
                                                   const float* __restrict__ W,
                                                   __half* __restrict__ y16) {
    int lane = threadIdx.x & 63;
    int wave = (blockIdx.x << 2) | (threadIdx.x >> 6);

    float Wreg[D];
#pragma unroll
    for (int k = 0; k < D; k++) Wreg[k] = W[k * D + lane];

    for (int n = wave; n < N_NODES; n += YBLK * 4) {
        float hv = x[(size_t)n * D + lane] * snorm[n];
        int hb = __float_as_int(hv);
        float p0 = 0.f, p1 = 0.f, p2 = 0.f, p3 = 0.f;
#pragma unroll
        for (int k = 0; k < D; k += 4) {
            p0 = fmaf(__int_as_float(__builtin_amdgcn_readlane(hb, k + 0)), Wreg[k + 0], p0);
            p1 = fmaf(__int_as_float(__builtin_amdgcn_readlane(hb, k + 1)), Wreg[k + 1], p1);
            p2 = fmaf(__int_as_float(__builtin_amdgcn_readlane(hb, k + 2)), Wreg[k + 2], p2);
            p3 = fmaf(__int_as_float(__builtin_amdgcn_readlane(hb, k + 3)), Wreg[k + 3], p3);
        }
        y16[(size_t)n * D + lane] = __float2half((p0 + p1) + (p2 + p3));
    }
}

// Pass 6: out[n] = dnorm[n] * sum_{in-edges} y16[src] + b. Wave per node,
// lane = feature. 128 B/edge, 1 load + cvt + add per edge, zero atomics.
#define GBLK 2048
__global__ __launch_bounds__(256, 8) void gather_kernel(const __half* __restrict__ y16,
                                                        const int* __restrict__ ssrc,
                                                        const int* __restrict__ base,
                                                        const int* __restrict__ rend,
                                                        const float* __restrict__ dnorm,
                                                        const float* __restrict__ b,
                                                        float* __restrict__ out) {
    int lane = threadIdx.x & 63;
    int wave = (blockIdx.x << 2) | (threadIdx.x >> 6);
    float breg = b[lane];
    const __half* yl = y16 + lane;

    for (int n = wave; n < N_NODES; n += GBLK * 4) {
        int beg = base[n];
        int end = rend[n];
        float a0 = 0.f, a1 = 0.f, a2 = 0.f, a3 = 0.f;
        float a4 = 0.f, a5 = 0.f, a6 = 0.f, a7 = 0.f;
        int i = beg;
        for (; i + 8 <= end; i += 8) {   // 8 row-loads in flight
            int s0 = ssrc[i],     s1 = ssrc[i + 1], s2 = ssrc[i + 2], s3 = ssrc[i + 3];
            int s4 = ssrc[i + 4], s5 = ssrc[i + 5], s6 = ssrc[i + 6], s7 = ssrc[i + 7];
            a0 += __half2float(yl[(size_t)s0 * D]);
            a1 += __half2float(yl[(size_t)s1 * D]);
            a2 += __half2float(yl[(size_t)s2 * D]);
            a3 += __half2float(yl[(size_t)s3 * D]);
            a4 += __half2float(yl[(size_t)s4 * D]);
            a5 += __half2float(yl[(size_t)s5 * D]);
            a6 += __half2float(yl[(size_t)s6 * D]);
            a7 += __half2float(yl[(size_t)s7 * D]);
        }
        for (; i + 4 <= end; i += 4) {
            int s0 = ssrc[i], s1 = ssrc[i + 1], s2 = ssrc[i + 2], s3 = ssrc[i + 3];
            a0 += __half2float(yl[(size_t)s0 * D]);
            a1 += __half2float(yl[(size_t)s1 * D]);
            a2 += __half2float(yl[(size_t)s2 * D]);
            a3 += __half2float(yl[(size_t)s3 * D]);
        }
        for (; i < end; ++i) {
            a0 += __half2float(yl[(size_t)ssrc[i] * D]);
        }
        float acc = ((a0 + a4) + (a1 + a5)) + ((a2 + a6) + (a3 + a7));
        out[(size_t)n * D + lane] = fmaf(acc, dnorm[n], breg);
    }
}

extern "C" void kernel_launch(void* const* d_in, const int* in_sizes, int n_in,
                              void* d_out, int out_size, void* d_ws, size_t ws_size,
                              hipStream_t stream) {
    const float* x   = (const float*)d_in[0];
    const int*   src = (const int*)d_in[1];
    const int*   dst = (const int*)d_in[2];
    const float* W   = (const float*)d_in[3];
    const float* b   = (const float*)d_in[4];
    float* out = (float*)d_out;

    char* ws = (char*)d_ws;
    int*          ctr   = (int*)(ws + CTR_OFF);
    int*          base  = (int*)(ws + BASE_OFF);
    int*          rend  = (int*)(ws + END_OFF);
    float*        snorm = (float*)(ws + SNORM_OFF);
    float*        dnorm = (float*)(ws + DNORM_OFF);
    unsigned int* INW   = (unsigned int*)(ws + INW_OFF);
    unsigned int* OUTW  = (unsigned int*)(ws + OUTW_OFF);
    int*          ssrc  = (int*)(ws + SSRC_OFF);
    unsigned int* part  = (unsigned int*)(ws + PART_OFF);
    __half*       y16   = (__half*)(ws + Y16_OFF);   // aliases part (dead after fill)

    hipMemsetAsync(d_ws, 0, ZERO_BYTES, stream);     // only the scan counter

    degree_lds_kernel<<<2 * SLICES, 256, 0, stream>>>((const int4*)src,
                                                      (const int4*)dst, part);
    merge_kernel<<<(12500 + 255) / 256, 256, 0, stream>>>(part, INW, OUTW);
    scan_kernel<<<(N_NODES + 255) / 256, 256, 0, stream>>>(INW, OUTW, base, rend,
                                                           snorm, dnorm, ctr);
    fill_kernel<<<SLICES, 256, 0, stream>>>((const int4*)src, (const int4*)dst,
                                            part, base, ssrc);
    y_kernel<<<YBLK, 256, 0, stream>>>(x, snorm, W, y16);
    gather_kernel<<<GBLK, 256, 0, stream>>>(y16, ssrc, base, rend, dnorm, b, out);
}

// Round 5
// 161.869 us; speedup vs baseline: 2.2086x; 1.0608x over previous
//
#include <hip/hip_runtime.h>
#include <hip/hip_fp16.h>

#define N_NODES 50000
#define N_EDGES 800000
#define D 64

#define SLICES 80                      // edge slices per role (src/dst)
#define I4S (N_EDGES / 4 / SLICES)     // 2500 int4 per slice (10000 edges)
#define NWORDS 12512                   // ceil(50000/4)=12500 words, padded to /4

typedef float vfloat2 __attribute__((ext_vector_type(2)));  // clang-native, OK for nontemporal builtins

// ---------------------------------------------------------------------------
// Workspace layout (bytes), total ~12.0 MB, all offsets 256-aligned:
//   [0,        64)        ctr    : int (scan counter; zeroed by degree_lds)
//   [256,      200256)    base   : int[N_NODES]    CSR row start
//   [200320,   400320)    rend   : int[N_NODES]    CSR row end
//   [400384,   600384)    snorm  : float[N_NODES]
//   [600448,   800448)    dnorm  : float[N_NODES]
//   [800512,   4000512)   ssrc   : int[N_EDGES]    src ids grouped by dst
//   [4000768,  12008448)  partial: uint[160][NWORDS] byte hists → prefixes
//   [4000768,  10400768)  y16    : half[N_NODES*D] (ALIASES partial; partial
//                                  is dead once fill_kernel has run)
// ---------------------------------------------------------------------------
#define CTR_OFF    0
#define BASE_OFF   256
#define END_OFF    200320
#define SNORM_OFF  400384
#define DNORM_OFF  600448
#define SSRC_OFF   800512
#define PART_OFF   4000768
#define Y16_OFF    PART_OFF

// Pass 1: per-slice byte-packed degree histograms in LDS. No fabric atomics.
// Block b: role = b&1 (0=src/outdeg, 1=dst/indeg), slice = b>>1.
// Block 0 also zeroes the scan counter (replaces the hipMemsetAsync dispatch).
__global__ __launch_bounds__(256) void degree_lds_kernel(const int4* __restrict__ src4,
                                                         const int4* __restrict__ dst4,
                                                         unsigned int* __restrict__ partial,
                                                         int* __restrict__ ctr) {
    __shared__ unsigned int hist[NWORDS];
    int tid = threadIdx.x;
    if (blockIdx.x == 0 && tid == 0) *ctr = 0;
    uint4* h4 = (uint4*)hist;
    for (int i = tid; i < NWORDS / 4; i += 256) h4[i] = make_uint4(0, 0, 0, 0);
    __syncthreads();

    int role  = blockIdx.x & 1;
    int slice = blockIdx.x >> 1;
    const int4* e = role ? dst4 : src4;
    int beg = slice * I4S, end = beg + I4S;
    for (int i = beg + tid; i < end; i += 256) {
        int4 v = e[i];
        atomicAdd(&hist[v.x >> 2], 1u << ((v.x & 3) * 8));
        atomicAdd(&hist[v.y >> 2], 1u << ((v.y & 3) * 8));
        atomicAdd(&hist[v.z >> 2], 1u << ((v.z & 3) * 8));
        atomicAdd(&hist[v.w >> 2], 1u << ((v.w & 3) * 8));
    }
    __syncthreads();

    uint4* p4 = (uint4*)(partial + (size_t)blockIdx.x * NWORDS);
    for (int i = tid; i < NWORDS / 4; i += 256) p4[i] = h4[i];
}

// Pass 2 (fused merge + scan): thread per word (4 nodes). Sums packed degrees
// over all slices, rewrites dst-role partials in place to per-slice EXCLUSIVE
// prefixes (byte adds; cumulative <= indeg < 255, no carry), then wave-scans
// the 4-node sums for CSR bases and writes all node arrays as int4/float4.
__global__ __launch_bounds__(256) void merge_scan_kernel(unsigned int* __restrict__ partial,
                                                         int* __restrict__ base,
                                                         int* __restrict__ rend,
                                                         float* __restrict__ snorm,
                                                         float* __restrict__ dnorm,
                                                         int* __restrict__ ctr) {
    int w = blockIdx.x * blockDim.x + threadIdx.x;
    int lane = threadIdx.x & 63;
    unsigned int accin = 0, accout = 0;
    if (w < 12500) {
        unsigned int* po = partial + w;            // src role: slice index 2s
        unsigned int* pd = partial + NWORDS + w;   // dst role: slice index 2s+1
#pragma unroll 4
        for (int s = 0; s < SLICES; s++) {
            size_t off = (size_t)(2 * s) * NWORDS;
            accout += po[off];
            unsigned int v = pd[off];
            pd[off] = accin;                       // exclusive prefix before slice s
            accin += v;
        }
    }
    int d0 = accin & 0xFF, d1 = (accin >> 8) & 0xFF,
        d2 = (accin >> 16) & 0xFF, d3 = (accin >> 24) & 0xFF;
    int tsum = d0 + d1 + d2 + d3;
    int run = tsum;  // inclusive wave scan of per-thread totals
#pragma unroll
    for (int off = 1; off < 64; off <<= 1) {
        int v = __shfl_up(run, off);
        if (lane >= off) run += v;
    }
    int wtot = __shfl(run, 63);
    int wbase = 0;
    if (lane == 63) wbase = atomicAdd(ctr, wtot);
    wbase = __shfl(wbase, 63);
    if (w < 12500) {
        int b0 = wbase + run - tsum;  // exclusive across threads
        int b1 = b0 + d0, b2 = b1 + d1, b3 = b2 + d2;
        ((int4*)base)[w] = make_int4(b0, b1, b2, b3);
        ((int4*)rend)[w] = make_int4(b1, b2, b3, b3 + d3);
        ((float4*)dnorm)[w] = make_float4(rsqrtf(fmaxf((float)d0, 1.f)),
                                          rsqrtf(fmaxf((float)d1, 1.f)),
                                          rsqrtf(fmaxf((float)d2, 1.f)),
                                          rsqrtf(fmaxf((float)d3, 1.f)));
        int o0 = accout & 0xFF, o1 = (accout >> 8) & 0xFF,
            o2 = (accout >> 16) & 0xFF, o3 = (accout >> 24) & 0xFF;
        ((float4*)snorm)[w] = make_float4(rsqrtf(fmaxf((float)o0, 1.f)),
                                          rsqrtf(fmaxf((float)o1, 1.f)),
                                          rsqrtf(fmaxf((float)o2, 1.f)),
                                          rsqrtf(fmaxf((float)o3, 1.f)));
    }
}

// Pass 3: CSR fill, zero fabric atomics. Block = dst slice; position =
// base[t] + per-slice exclusive prefix + LDS-local occurrence (byte-packed).
__global__ __launch_bounds__(256) void fill_kernel(const int4* __restrict__ src4,
                                                   const int4* __restrict__ dst4,
                                                   const unsigned int* __restrict__ partial,
                                                   const int* __restrict__ base,
                                                   int* __restrict__ ssrc) {
    __shared__ unsigned int hist[NWORDS];
    int tid = threadIdx.x;
    uint4* h4 = (uint4*)hist;
    for (int i = tid; i < NWORDS / 4; i += 256) h4[i] = make_uint4(0, 0, 0, 0);
    __syncthreads();

    int s = blockIdx.x;
    const int4* sp = src4 + (size_t)s * I4S;
    const int4* dp = dst4 + (size_t)s * I4S;
    const unsigned int* pref = partial + (size_t)(2 * s + 1) * NWORDS;

    for (int i = tid; i < I4S; i += 256) {
        int4 sv = sp[i], tv = dp[i];
#define FILL_ONE(T, S)                                                        \
        {                                                                     \
            int t = (T); int sh = (t & 3) * 8;                                \
            unsigned int old = atomicAdd(&hist[t >> 2], 1u << sh);            \
            int local = (old >> sh) & 0xFF;                                   \
            int p = base[t] + (int)((pref[t >> 2] >> sh) & 0xFFu) + local;    \
            ssrc[p] = (S);                                                    \
        }
        FILL_ONE(tv.x, sv.x)
        FILL_ONE(tv.y, sv.y)
        FILL_ONE(tv.z, sv.z)
        FILL_ONE(tv.w, sv.w)
#undef FILL_ONE
    }
}

// Pass 4: y = (x * snorm) @ W, stored fp16. Wave per node, lane = out column;
// W one column per lane in VGPRs, x-row broadcast via v_readlane.
#define YBLK 1024
__global__ __launch_bounds__(256, 4) void y_kernel(const float* __restrict__ x,
                                                   const float* __restrict__ snorm,
                                                   const float* __restrict__ W,
                                                   __half* __restrict__ y16) {
    int lane = threadIdx.x & 63;
    int wave = (blockIdx.x << 2) | (threadIdx.x >> 6);

    float Wreg[D];
#pragma unroll
    for (int k = 0; k < D; k++) Wreg[k] = W[k * D + lane];

    for (int n = wave; n < N_NODES; n += YBLK * 4) {
        float hv = x[(size_t)n * D + lane] * snorm[n];
        int hb = __float_as_int(hv);
        float p0 = 0.f, p1 = 0.f, p2 = 0.f, p3 = 0.f;
#pragma unroll
        for (int k = 0; k < D; k += 4) {
            p0 = fmaf(__int_as_float(__builtin_amdgcn_readlane(hb, k + 0)), Wreg[k + 0], p0);
            p1 = fmaf(__int_as_float(__builtin_amdgcn_readlane(hb, k + 1)), Wreg[k + 1], p1);
            p2 = fmaf(__int_as_float(__builtin_amdgcn_readlane(hb, k + 2)), Wreg[k + 2], p2);
            p3 = fmaf(__int_as_float(__builtin_amdgcn_readlane(hb, k + 3)), Wreg[k + 3], p3);
        }
        y16[(size_t)n * D + lane] = __float2half((p0 + p1) + (p2 + p3));
    }
}

// Pass 5: out[n] = dnorm[n] * sum_{in-edges} y16[src] + b.
// Pair layout: even lanes cover edge i, odd lanes edge i+1; each lane loads a
// __half2 (features 2*col, 2*col+1 of its edge). One wave-load = TWO rows, so
// the 8-deep pipeline keeps 16 edges in flight. Combine via shfl(lane^1);
// coalesced vfloat2 nontemporal stores (keep y16 hot in L2).
#define GBLK 2048
__global__ __launch_bounds__(256, 8) void gather_kernel(const __half2* __restrict__ y2,
                                                        const int* __restrict__ ssrc,
                                                        const int* __restrict__ base,
                                                        const int* __restrict__ rend,
                                                        const float* __restrict__ dnorm,
                                                        const float* __restrict__ b,
                                                        float* __restrict__ out) {
    int lane = threadIdx.x & 63;
    int half = lane & 1;       // which edge of the pair
    int col  = lane >> 1;      // half2 column: features {2col, 2col+1}
    int wave = (blockIdx.x << 2) | (threadIdx.x >> 6);

    float2 b2 = ((const float2*)b)[col];
    const __half2* yl = y2 + col;   // row stride = 32 half2

    for (int n = wave; n < N_NODES; n += GBLK * 4) {
        int beg = base[n], end = rend[n];
        float ax0 = 0.f, ay0 = 0.f, ax1 = 0.f, ay1 = 0.f;
        float ax2 = 0.f, ay2 = 0.f, ax3 = 0.f, ay3 = 0.f;
        float ax4 = 0.f, ay4 = 0.f, ax5 = 0.f, ay5 = 0.f;
        float ax6 = 0.f, ay6 = 0.f, ax7 = 0.f, ay7 = 0.f;
        int i0 = beg;
        for (; i0 + 16 <= end; i0 += 16) {   // 16 edges, 8 loads in flight
            int e = i0 + half;
            int s0 = ssrc[e],      s1 = ssrc[e + 2],  s2 = ssrc[e + 4],  s3 = ssrc[e + 6];
            int s4 = ssrc[e + 8],  s5 = ssrc[e + 10], s6 = ssrc[e + 12], s7 = ssrc[e + 14];
            float2 f0 = __half22float2(yl[(size_t)s0 * 32]);
            float2 f1 = __half22float2(yl[(size_t)s1 * 32]);
            float2 f2 = __half22float2(yl[(size_t)s2 * 32]);
            float2 f3 = __half22float2(yl[(size_t)s3 * 32]);
            float2 f4 = __half22float2(yl[(size_t)s4 * 32]);
            float2 f5 = __half22float2(yl[(size_t)s5 * 32]);
            float2 f6 = __half22float2(yl[(size_t)s6 * 32]);
            float2 f7 = __half22float2(yl[(size_t)s7 * 32]);
            ax0 += f0.x; ay0 += f0.y; ax1 += f1.x; ay1 += f1.y;
            ax2 += f2.x; ay2 += f2.y; ax3 += f3.x; ay3 += f3.y;
            ax4 += f4.x; ay4 += f4.y; ax5 += f5.x; ay5 += f5.y;
            ax6 += f6.x; ay6 += f6.y; ax7 += f7.x; ay7 += f7.y;
        }
        for (; i0 + 2 <= end; i0 += 2) {     // full pairs
            int s = ssrc[i0 + half];
            float2 f = __half22float2(yl[(size_t)s * 32]);
            ax0 += f.x; ay0 += f.y;
        }
        if (i0 < end && half == 0) {         // odd leftover edge
            int s = ssrc[i0];
            float2 f = __half22float2(yl[(size_t)s * 32]);
            ax1 += f.x; ay1 += f.y;
        }
        float sx = ((ax0 + ax1) + (ax2 + ax3)) + ((ax4 + ax5) + (ax6 + ax7));
        float sy = ((ay0 + ay1) + (ay2 + ay3)) + ((ay4 + ay5) + (ay6 + ay7));
        sx += __shfl(sx, lane ^ 1);
        sy += __shfl(sy, lane ^ 1);
        if (half == 0) {
            float dn = dnorm[n];
            vfloat2 o;
            o.x = fmaf(sx, dn, b2.x);
            o.y = fmaf(sy, dn, b2.y);
            __builtin_nontemporal_store(o, (vfloat2*)(out + (size_t)n * D) + col);
        }
    }
}

extern "C" void kernel_launch(void* const* d_in, const int* in_sizes, int n_in,
                              void* d_out, int out_size, void* d_ws, size_t ws_size,
                              hipStream_t stream) {
    const float* x   = (const float*)d_in[0];
    const int*   src = (const int*)d_in[1];
    const int*   dst = (const int*)d_in[2];
    const float* W   = (const float*)d_in[3];
    const float* b   = (const float*)d_in[4];
    float* out = (float*)d_out;

    char* ws = (char*)d_ws;
    int*          ctr   = (int*)(ws + CTR_OFF);
    int*          base  = (int*)(ws + BASE_OFF);
    int*          rend  = (int*)(ws + END_OFF);
    float*        snorm = (float*)(ws + SNORM_OFF);
    float*        dnorm = (float*)(ws + DNORM_OFF);
    int*          ssrc  = (int*)(ws + SSRC_OFF);
    unsigned int* part  = (unsigned int*)(ws + PART_OFF);
    __half*       y16   = (__half*)(ws + Y16_OFF);   // aliases part (dead after fill)

    degree_lds_kernel<<<2 * SLICES, 256, 0, stream>>>((const int4*)src,
                                                      (const int4*)dst, part, ctr);
    merge_scan_kernel<<<(12500 + 255) / 256, 256, 0, stream>>>(part, base, rend,
                                                               snorm, dnorm, ctr);
    fill_kernel<<<SLICES, 256, 0, stream>>>((const int4*)src, (const int4*)dst,
                                            part, base, ssrc);
    y_kernel<<<YBLK, 256, 0, stream>>>(x, snorm, W, y16);
    gather_kernel<<<GBLK, 256, 0, stream>>>((const __half2*)y16, ssrc, base, rend,
                                            dnorm, b, out);
}